// Round 3
// baseline (701.724 us; speedup 1.0000x reference)
//
#include <hip/hip_runtime.h>
#include <cstdint>
#include <cstddef>

#define BB 8
#define SS 1024
#define HH 768
#define TT 8
#define DII 64
#define HIDD 128
#define KSP 8
#define NHEADS 2
#define NNODES 9
#define GDIM 256   // NHEADS*HIDD
#define CDIM 1024  // TT*2*DII == HH+GDIM
#define DAUGP 96   // 64 rope + 16 gauss + 16 zero pad (3 x 32-k MFMA slabs)
#define NEGV 1e12f

using bf16x8 = __attribute__((ext_vector_type(8))) __bf16;
using f32x4  = __attribute__((ext_vector_type(4))) float;

static __device__ inline unsigned short f2bf(float x) {
  union { float f; unsigned u; } v; v.f = x;
  unsigned r = v.u + 0x7fff + ((v.u >> 16) & 1);
  return (unsigned short)(r >> 16);
}
static __device__ inline float bf2f(unsigned short x) {
  union { float f; unsigned u; } v; v.u = (unsigned)x << 16; return v.f;
}

// ------- kc: fused conversions: hidden->bf16 rows, dense_W top -> bf16 transposed -------
__global__ void kc_convert(const float* __restrict__ hidden, const float* __restrict__ dense_W,
                           unsigned short* __restrict__ hbf, unsigned short* __restrict__ WtopT) {
  __shared__ float t[32][33];
  int bx = blockIdx.x, tid = threadIdx.x;
  if (bx < 6144) {                                   // hidden convert: 8*1024*768/4/256
    int idx = bx * 256 + tid;
    float4 v = *(const float4*)(hidden + (size_t)idx * 4);
    ushort4 o; o.x = f2bf(v.x); o.y = f2bf(v.y); o.z = f2bf(v.z); o.w = f2bf(v.w);
    *(ushort4*)(hbf + (size_t)idx * 4) = o;
  } else {                                           // Wtop transpose: 24*32 blocks
    int bb = bx - 6144;
    int k0 = (bb % 24) * 32, n0 = (bb / 24) * 32;
    int r = tid >> 3, c4 = (tid & 7) * 4;
    float4 v = *(const float4*)&dense_W[(size_t)(k0 + r) * CDIM + n0 + c4];
    t[r][c4 + 0] = v.x; t[r][c4 + 1] = v.y; t[r][c4 + 2] = v.z; t[r][c4 + 3] = v.w;
    __syncthreads();
    ushort4 o;
    o.x = f2bf(t[c4 + 0][r]); o.y = f2bf(t[c4 + 1][r]);
    o.z = f2bf(t[c4 + 2][r]); o.w = f2bf(t[c4 + 3][r]);
    *(ushort4*)&WtopT[(size_t)(n0 + r) * HH + k0 + c4] = o;
  }
}

// ------- k1: fused partial col-sums + cover (z<16) and span means (z==16) ---------------
__global__ void k1_stats(const float* __restrict__ hidden, const int* __restrict__ spans,
                         float* __restrict__ part, float* __restrict__ nodes,
                         float* __restrict__ cover) {
  __shared__ int sp[KSP * 3];
  int z = blockIdx.x, b = blockIdx.y, tid = threadIdx.x;
  const float* hb = hidden + (size_t)b * SS * HH;
  if (z < 16) {
    #pragma unroll
    for (int j = 0; j < 3; j++) {
      int c = tid + j * 256;
      float acc = 0.f;
      for (int r = z * 64; r < z * 64 + 64; r++) acc += hb[(size_t)r * HH + c];
      part[((size_t)b * 16 + z) * HH + c] = acc;
    }
    if (tid < 64) {
      int s = z * 64 + tid;
      float c = 0.f;
      #pragma unroll
      for (int k = 0; k < KSP; k++) {
        int st = spans[(b * KSP + k) * 3], en = spans[(b * KSP + k) * 3 + 1];
        c += (s >= st && s <= en) ? 1.f : 0.f;
      }
      cover[b * SS + s] = c;
    }
  } else {
    if (tid < KSP * 3) sp[tid] = spans[b * KSP * 3 + tid];
    __syncthreads();
    for (int k = 0; k < KSP; k++) {
      int st = sp[k * 3], en = sp[k * 3 + 1];
      float inv = 1.f / (float)(en - st + 1);
      for (int c = tid; c < HH; c += 256) {
        float a = 0.f;
        for (int s = st; s <= en; s++) a += hb[(size_t)s * HH + c];
        nodes[((size_t)b * NNODES + (k + 1)) * HH + c] = a * inv;
      }
    }
  }
}

// ------- k2: reduce global mean + two GAT layers + LN + E2 ------------------------------
__global__ __launch_bounds__(256) void k2_gat(
    const float* __restrict__ part, const float* __restrict__ nodes_g,
    const int* __restrict__ spans,
    const float* __restrict__ W1, const float* __restrict__ a_src1,
    const float* __restrict__ a_dst1, const float* __restrict__ b1,
    const float* __restrict__ ln_g, const float* __restrict__ ln_b,
    const float* __restrict__ W2, const float* __restrict__ a_src2,
    const float* __restrict__ a_dst2, const float* __restrict__ b2,
    const float* __restrict__ dense_W, float* __restrict__ E2) {
  int b = blockIdx.x, tid = threadIdx.x;
  __shared__ float nod[NNODES * HH];
  __shared__ float hbuf[NNODES * GDIM];
  __shared__ float gbuf[NNODES * GDIM];
  __shared__ float asrc[NNODES * NHEADS], adst[NNODES * NHEADS];
  __shared__ float adjm[NNODES * NNODES];
  __shared__ float attn[NNODES * NNODES * NHEADS];
  __shared__ float mu_s[NNODES], rs_s[NNODES];
  __shared__ float enh[GDIM];
  __shared__ int sp[KSP * 3];
  if (tid < KSP * 3) sp[tid] = spans[b * KSP * 3 + tid];
  #pragma unroll
  for (int j = 0; j < 3; j++) {          // node0 = global mean from partials
    int c = tid + j * 256;
    float s = 0.f;
    for (int z = 0; z < 16; z++) s += part[((size_t)b * 16 + z) * HH + c];
    nod[c] = s / (float)SS;
  }
  for (int i = tid; i < (NNODES - 1) * HH; i += 256)
    nod[HH + i] = nodes_g[(size_t)b * NNODES * HH + HH + i];
  __syncthreads();
  {
    float acc[NNODES];
    #pragma unroll
    for (int n = 0; n < NNODES; n++) acc[n] = 0.f;
    for (int d = 0; d < HH; d++) {
      float w = W1[(size_t)d * GDIM + tid];
      #pragma unroll
      for (int n = 0; n < NNODES; n++) acc[n] += nod[n * HH + d] * w;
    }
    #pragma unroll
    for (int n = 0; n < NNODES; n++) hbuf[n * GDIM + tid] = acc[n];
  }
  if (tid < NNODES * NNODES) {
    int i = tid / NNODES, j = tid % NNODES;
    float a = (i == j) ? 1.f : 0.f;
    if (i > 0 && j == 0) a += 1.f;
    if (i == 0 && j > 0) a += 1.f;
    if (i > 0 && j > 0 && i != j) {
      int x = j - 1, y = i - 1;
      int sx = sp[x * 3], ex = sp[x * 3 + 1], sy = sp[y * 3], ey = sp[y * 3 + 1];
      bool same = (sx == sy) && (ex == ey);
      if (sx <= sy && ey <= ex && !same) a += 2.f;
    }
    adjm[tid] = a;
  }
  __syncthreads();
  if (tid < NNODES * NHEADS) {
    int n = tid >> 1, hd = tid & 1;
    float sa = 0.f, sd = 0.f;
    for (int f = 0; f < HIDD; f++) {
      float v = hbuf[n * GDIM + hd * HIDD + f];
      sa += v * a_src1[hd * HIDD + f];
      sd += v * a_dst1[hd * HIDD + f];
    }
    asrc[tid] = sa; adst[tid] = sd;
  }
  __syncthreads();
  if (tid < NNODES * NHEADS) {
    int d = tid >> 1, hd = tid & 1;
    float sc[NNODES]; float mx = -1e30f;
    for (int s2 = 0; s2 < NNODES; s2++) {
      float a = adjm[d * NNODES + s2]; float v;
      if (a > 0.f) {
        float e = adst[d * 2 + hd] + asrc[s2 * 2 + hd];
        e = (e > 0.f) ? e : 0.2f * e;
        v = e + __logf(a);
      } else v = -1e30f;
      sc[s2] = v; mx = fmaxf(mx, v);
    }
    float ssum = 0.f;
    for (int s2 = 0; s2 < NNODES; s2++) { float ex = __expf(sc[s2] - mx); sc[s2] = ex; ssum += ex; }
    float inv = 1.f / ssum;
    for (int s2 = 0; s2 < NNODES; s2++) attn[(d * NNODES + s2) * NHEADS + hd] = sc[s2] * inv;
  }
  __syncthreads();
  {
    int hd = tid >> 7;
    float bb = b1[tid];
    for (int d = 0; d < NNODES; d++) {
      float acc = bb;
      #pragma unroll
      for (int s2 = 0; s2 < NNODES; s2++)
        acc += attn[(d * NNODES + s2) * NHEADS + hd] * hbuf[s2 * GDIM + tid];
      gbuf[d * GDIM + tid] = fmaxf(acc, 0.f);
    }
  }
  __syncthreads();
  if (tid < NNODES) {
    float s1 = 0.f, s2v = 0.f;
    for (int o = 0; o < GDIM; o++) { float v = gbuf[tid * GDIM + o]; s1 += v; s2v += v * v; }
    float mu = s1 / (float)GDIM;
    float var = s2v / (float)GDIM - mu * mu;
    mu_s[tid] = mu; rs_s[tid] = rsqrtf(var + 1e-5f);
  }
  __syncthreads();
  {
    float g = ln_g[tid], bt = ln_b[tid];
    for (int d = 0; d < NNODES; d++)
      gbuf[d * GDIM + tid] = (gbuf[d * GDIM + tid] - mu_s[d]) * rs_s[d] * g + bt;
  }
  __syncthreads();
  {
    float acc[NNODES];
    #pragma unroll
    for (int n = 0; n < NNODES; n++) acc[n] = 0.f;
    for (int d = 0; d < GDIM; d++) {
      float w = W2[(size_t)d * GDIM + tid];
      #pragma unroll
      for (int n = 0; n < NNODES; n++) acc[n] += gbuf[n * GDIM + d] * w;
    }
    #pragma unroll
    for (int n = 0; n < NNODES; n++) hbuf[n * GDIM + tid] = acc[n];
  }
  __syncthreads();
  if (tid < NNODES * NHEADS) {
    int n = tid >> 1, hd = tid & 1;
    float sa = 0.f, sd = 0.f;
    for (int f = 0; f < HIDD; f++) {
      float v = hbuf[n * GDIM + hd * HIDD + f];
      sa += v * a_src2[hd * HIDD + f];
      sd += v * a_dst2[hd * HIDD + f];
    }
    asrc[tid] = sa; adst[tid] = sd;
  }
  __syncthreads();
  if (tid < NNODES * NHEADS) {
    int d = tid >> 1, hd = tid & 1;
    float sc[NNODES]; float mx = -1e30f;
    for (int s2 = 0; s2 < NNODES; s2++) {
      float a = adjm[d * NNODES + s2]; float v;
      if (a > 0.f) {
        float e = adst[d * 2 + hd] + asrc[s2 * 2 + hd];
        e = (e > 0.f) ? e : 0.2f * e;
        v = e + __logf(a);
      } else v = -1e30f;
      sc[s2] = v; mx = fmaxf(mx, v);
    }
    float ssum = 0.f;
    for (int s2 = 0; s2 < NNODES; s2++) { float ex = __expf(sc[s2] - mx); sc[s2] = ex; ssum += ex; }
    float inv = 1.f / ssum;
    for (int s2 = 0; s2 < NNODES; s2++) attn[(d * NNODES + s2) * NHEADS + hd] = sc[s2] * inv;
  }
  __syncthreads();
  {
    int hd = tid >> 7;
    float bb = b2[tid];
    float msum = 0.f;
    for (int d = 0; d < NNODES; d++) {
      float acc = bb;
      #pragma unroll
      for (int s2 = 0; s2 < NNODES; s2++)
        acc += attn[(d * NNODES + s2) * NHEADS + hd] * hbuf[s2 * GDIM + tid];
      msum += fmaxf(acc, 0.f);
    }
    enh[tid] = msum / 9.f;
  }
  __syncthreads();
  for (int o = tid; o < CDIM; o += 256) {
    float acc = 0.f;
    for (int d = 0; d < GDIM; d++)
      acc += enh[d] * dense_W[(size_t)(HH + d) * CDIM + o];
    E2[b * CDIM + o] = acc;
  }
}

// ------- k3: qk(bf16) = hidden @ Wtop (MFMA, transposed D for vector stores) ------------
__global__ __launch_bounds__(256) void k3_dense(
    const unsigned short* __restrict__ hbf, const unsigned short* __restrict__ WtopT,
    const float* __restrict__ dense_b, const float* __restrict__ cover,
    const float* __restrict__ E2, unsigned short* __restrict__ qkb) {
  __shared__ unsigned short As[128 * 40];  // hidden rows [m][kpad=40]
  __shared__ unsigned short Bs[128 * 40];  // Wtop rows   [n][kpad=40]
  int tid = threadIdx.x;
  int n0 = blockIdx.x * 128, m0 = blockIdx.y * 128;
  int wave = tid >> 6, lane = tid & 63;
  int wm = wave >> 1, wn = wave & 1;
  int colL = lane & 15, quad = lane >> 4;
  f32x4 acc[4][4];                          // [tn][tq]: D[row=n][col=m]
  #pragma unroll
  for (int i = 0; i < 4; i++)
    #pragma unroll
    for (int j = 0; j < 4; j++) { acc[i][j][0] = 0.f; acc[i][j][1] = 0.f; acc[i][j][2] = 0.f; acc[i][j][3] = 0.f; }
  for (int k0 = 0; k0 < HH; k0 += 32) {
    uint4 va[2], vb[2];
    #pragma unroll
    for (int it = 0; it < 2; it++) {
      int idx = tid + it * 256;
      int r = idx >> 2, seg = idx & 3;
      va[it] = *(const uint4*)(hbf + (size_t)(m0 + r) * HH + k0 + seg * 8);
      vb[it] = *(const uint4*)(WtopT + (size_t)(n0 + r) * HH + k0 + seg * 8);
    }
    __syncthreads();
    #pragma unroll
    for (int it = 0; it < 2; it++) {
      int idx = tid + it * 256;
      int r = idx >> 2, seg = idx & 3;
      *(uint4*)&As[r * 40 + seg * 8] = va[it];
      *(uint4*)&Bs[r * 40 + seg * 8] = vb[it];
    }
    __syncthreads();
    bf16x8 af[4], bf[4];
    #pragma unroll
    for (int tn = 0; tn < 4; tn++)   // A operand = Wtop side (M dim = out col)
      af[tn] = *(const bf16x8*)&Bs[(wn * 64 + tn * 16 + colL) * 40 + quad * 8];
    #pragma unroll
    for (int tq = 0; tq < 4; tq++)   // B operand = hidden side (N dim = m row)
      bf[tq] = *(const bf16x8*)&As[(wm * 64 + tq * 16 + colL) * 40 + quad * 8];
    #pragma unroll
    for (int tn = 0; tn < 4; tn++)
      #pragma unroll
      for (int tq = 0; tq < 4; tq++)
        acc[tn][tq] = __builtin_amdgcn_mfma_f32_16x16x32_bf16(af[tn], bf[tq], acc[tn][tq], 0, 0, 0);
  }
  int b = m0 >> 10;
  #pragma unroll
  for (int tq = 0; tq < 4; tq++) {
    int m = m0 + wm * 64 + tq * 16 + colL;
    float cov = cover[m];
    #pragma unroll
    for (int tn = 0; tn < 4; tn++) {
      int nb = n0 + wn * 64 + tn * 16 + quad * 4;
      float4 e2 = *(const float4*)&E2[b * CDIM + nb];
      float4 db = *(const float4*)&dense_b[nb];
      ushort4 o;
      o.x = f2bf(acc[tn][tq][0] + cov * e2.x + db.x);
      o.y = f2bf(acc[tn][tq][1] + cov * e2.y + db.y);
      o.z = f2bf(acc[tn][tq][2] + cov * e2.z + db.z);
      o.w = f2bf(acc[tn][tq][3] + cov * e2.w + db.w);
      *(ushort4*)(qkb + (size_t)m * CDIM + nb) = o;
    }
  }
}

// ------- k4: RoPE + gauss -> Qa/Ka bf16 [bt][s][96], coalesced ---------------------------
__global__ void k4_ropeaug(const unsigned short* __restrict__ qkb, const int* __restrict__ spans,
                           const float* __restrict__ corr, const float* __restrict__ gc,
                           const float* __restrict__ gs, const float* __restrict__ gw,
                           unsigned short* __restrict__ Qa, unsigned short* __restrict__ Ka) {
  int tid = threadIdx.x;
  int g = tid >> 5, lane = tid & 31;
  int row = blockIdx.x * 8 + g;
  int b = row >> 10, s = row & 1023;
  const unsigned short* qrow = qkb + (size_t)row * CDIM;
  int d = lane * 4;            // 0..124
  int dd = d & 63;
  int i0 = dd >> 1;
  const float L = 0.28782313662425576f;  // ln(10000)/32
  float inv0 = __expf(-(float)i0 * L), inv1 = __expf(-(float)(i0 + 1) * L);
  float s0, c0, s1, c1;
  __sincosf((float)s * inv0, &s0, &c0);
  __sincosf((float)s * inv1, &s1, &c1);
  unsigned short* dst = (d < 64) ? Qa : Ka;
  // tail lanes: 0..3 Qa gauss, 4..7 Qa pad, 8..11 Ka gauss, 12..15 Ka pad
  float ge[4]; int ets[4] = {0, 0, 0, 0};
  bool qa_side = lane < 8;
  int Lq = lane & 7;
  ge[0] = ge[1] = ge[2] = ge[3] = 0.f;
  if (lane < 16 && Lq < 4) {
    #pragma unroll
    for (int jj = 0; jj < 4; jj++) {
      int j = Lq * 4 + jj; int kp = j >> 1, c = j & 1;
      int st = spans[(b * KSP + kp) * 3], en = spans[(b * KSP + kp) * 3 + 1];
      ets[jj] = spans[(b * KSP + kp) * 3 + 2];
      float ref = qa_side ? (float)st : (float)en;
      float dx = ((float)s - ref - gc[c]) / gs[c];
      ge[jj] = gw[c] * __expf(-0.5f * dx * dx);
    }
  }
  #pragma unroll
  for (int t = 0; t < TT; t++) {
    ushort4 v = *(const ushort4*)(qrow + t * 128 + d);
    float x0 = bf2f(v.x), x1 = bf2f(v.y), x2 = bf2f(v.z), x3 = bf2f(v.w);
    ushort4 w;
    w.x = f2bf(x0 * c0 - x1 * s0);
    w.y = f2bf(x1 * c0 + x0 * s0);
    w.z = f2bf(x2 * c1 - x3 * s1);
    w.w = f2bf(x3 * c1 + x2 * s1);
    size_t base = ((size_t)(b * TT + t) * SS + s) * DAUGP;
    *(ushort4*)(dst + base + dd) = w;
    if (lane < 16) {
      ushort4 tw;
      if (Lq < 4) {
        if (qa_side) {
          tw.x = f2bf(corr[ets[0] * TT + t] * ge[0]);
          tw.y = f2bf(corr[ets[1] * TT + t] * ge[1]);
          tw.z = f2bf(corr[ets[2] * TT + t] * ge[2]);
          tw.w = f2bf(corr[ets[3] * TT + t] * ge[3]);
        } else {
          tw.x = f2bf(ge[0]); tw.y = f2bf(ge[1]); tw.z = f2bf(ge[2]); tw.w = f2bf(ge[3]);
        }
      } else { tw.x = 0; tw.y = 0; tw.z = 0; tw.w = 0; }
      unsigned short* tdst = qa_side ? Qa : Ka;
      *(ushort4*)(tdst + base + 64 + Lq * 4) = tw;
    }
  }
}

// ------- k5: logits = Qa @ Ka^T (MFMA, transposed D) + mask, float4 stores ---------------
__global__ __launch_bounds__(256) void k5_logits(
    const unsigned short* __restrict__ Qa, const unsigned short* __restrict__ Ka,
    const float* __restrict__ amask, float* __restrict__ out) {
  int bz = blockIdx.z; int b = bz >> 3;
  int n0 = blockIdx.x * 128, m0 = blockIdx.y * 128;
  int tid = threadIdx.x;
  if (n0 + 127 < m0) {
    int r0 = tid >> 5, c4 = (tid & 31) * 4;
    float4 pv = *(const float4*)&amask[b * SS + n0 + c4];
    float4 o;
    o.x = (-(1.f - pv.x) * NEGV - NEGV) * 0.125f;
    o.y = (-(1.f - pv.y) * NEGV - NEGV) * 0.125f;
    o.z = (-(1.f - pv.z) * NEGV - NEGV) * 0.125f;
    o.w = (-(1.f - pv.w) * NEGV - NEGV) * 0.125f;
    for (int r = r0; r < 128; r += 8)
      *(float4*)&out[((size_t)bz * SS + m0 + r) * SS + n0 + c4] = o;
    return;
  }
  __shared__ unsigned short Qs[128 * 104];   // [m][kpad=104]
  __shared__ unsigned short Ks[128 * 104];   // [n][kpad=104]
  const unsigned short* Qrow = Qa + ((size_t)bz * SS + m0) * DAUGP;
  const unsigned short* Krow = Ka + ((size_t)bz * SS + n0) * DAUGP;
  #pragma unroll
  for (int it = 0; it < 6; it++) {
    int idx = tid + it * 256;
    int r = idx / 12, seg = idx % 12;
    uint4 vq = *(const uint4*)(Qrow + (size_t)r * DAUGP + seg * 8);
    uint4 vk = *(const uint4*)(Krow + (size_t)r * DAUGP + seg * 8);
    *(uint4*)&Qs[r * 104 + seg * 8] = vq;
    *(uint4*)&Ks[r * 104 + seg * 8] = vk;
  }
  __syncthreads();
  int wave = tid >> 6, lane = tid & 63;
  int wm = wave >> 1, wn = wave & 1;
  int colL = lane & 15, quad = lane >> 4;
  f32x4 acc[4][4];                           // [tn][tq]: D[row=n][col=m]
  #pragma unroll
  for (int i = 0; i < 4; i++)
    #pragma unroll
    for (int j = 0; j < 4; j++) { acc[i][j][0] = 0.f; acc[i][j][1] = 0.f; acc[i][j][2] = 0.f; acc[i][j][3] = 0.f; }
  #pragma unroll
  for (int ks = 0; ks < 3; ks++) {
    bf16x8 af[4], bf[4];
    #pragma unroll
    for (int tn = 0; tn < 4; tn++)   // A operand = K side (M dim = out col n)
      af[tn] = *(const bf16x8*)&Ks[(wn * 64 + tn * 16 + colL) * 104 + ks * 32 + quad * 8];
    #pragma unroll
    for (int tq = 0; tq < 4; tq++)   // B operand = Q side (N dim = out row m)
      bf[tq] = *(const bf16x8*)&Qs[(wm * 64 + tq * 16 + colL) * 104 + ks * 32 + quad * 8];
    #pragma unroll
    for (int tn = 0; tn < 4; tn++)
      #pragma unroll
      for (int tq = 0; tq < 4; tq++)
        acc[tn][tq] = __builtin_amdgcn_mfma_f32_16x16x32_bf16(af[tn], bf[tq], acc[tn][tq], 0, 0, 0);
  }
  float4 pv[4]; int nb[4];
  #pragma unroll
  for (int tn = 0; tn < 4; tn++) {
    nb[tn] = n0 + wn * 64 + tn * 16 + quad * 4;
    pv[tn] = *(const float4*)&amask[b * SS + nb[tn]];
  }
  #pragma unroll
  for (int tq = 0; tq < 4; tq++) {
    int m = m0 + wm * 64 + tq * 16 + colL;
    float* orow = out + ((size_t)bz * SS + m) * SS;
    #pragma unroll
    for (int tn = 0; tn < 4; tn++) {
      float4 o;
      float v0 = acc[tn][tq][0] * pv[tn].x - (1.f - pv[tn].x) * NEGV; if (nb[tn] + 0 < m) v0 -= NEGV;
      float v1 = acc[tn][tq][1] * pv[tn].y - (1.f - pv[tn].y) * NEGV; if (nb[tn] + 1 < m) v1 -= NEGV;
      float v2 = acc[tn][tq][2] * pv[tn].z - (1.f - pv[tn].z) * NEGV; if (nb[tn] + 2 < m) v2 -= NEGV;
      float v3 = acc[tn][tq][3] * pv[tn].w - (1.f - pv[tn].w) * NEGV; if (nb[tn] + 3 < m) v3 -= NEGV;
      o.x = v0 * 0.125f; o.y = v1 * 0.125f; o.z = v2 * 0.125f; o.w = v3 * 0.125f;
      *(float4*)&orow[nb[tn]] = o;
    }
  }
}

extern "C" void kernel_launch(void* const* d_in, const int* in_sizes, int n_in,
                              void* d_out, int out_size, void* d_ws, size_t ws_size,
                              hipStream_t stream) {
  const float* hidden  = (const float*)d_in[0];
  const float* amask   = (const float*)d_in[1];
  const int*   spans   = (const int*)d_in[2];
  const float* W1      = (const float*)d_in[3];
  const float* a_src1  = (const float*)d_in[4];
  const float* a_dst1  = (const float*)d_in[5];
  const float* b1      = (const float*)d_in[6];
  const float* ln_g    = (const float*)d_in[7];
  const float* ln_b    = (const float*)d_in[8];
  const float* W2      = (const float*)d_in[9];
  const float* a_src2  = (const float*)d_in[10];
  const float* a_dst2  = (const float*)d_in[11];
  const float* b2      = (const float*)d_in[12];
  const float* dense_W = (const float*)d_in[13];
  const float* dense_b = (const float*)d_in[14];
  const float* gc      = (const float*)d_in[15];
  const float* gs      = (const float*)d_in[16];
  const float* gw      = (const float*)d_in[17];
  const float* corr    = (const float*)d_in[18];

  char* wsb = (char*)d_ws;
  unsigned short* qkb  = (unsigned short*)wsb;  wsb += (size_t)BB * SS * CDIM * 2;        // 16.8 MB
  unsigned short* hbf  = (unsigned short*)wsb;  wsb += (size_t)BB * SS * HH * 2;          // 12.6 MB
  unsigned short* WtopT= (unsigned short*)wsb;  wsb += (size_t)CDIM * HH * 2;             // 1.57 MB
  unsigned short* Qa   = (unsigned short*)wsb;  wsb += (size_t)BB * TT * SS * DAUGP * 2;  // 12.6 MB
  unsigned short* Ka   = (unsigned short*)wsb;  wsb += (size_t)BB * TT * SS * DAUGP * 2;  // 12.6 MB
  float* nodes         = (float*)wsb;           wsb += (size_t)BB * NNODES * HH * 4;
  float* cover         = (float*)wsb;           wsb += (size_t)BB * SS * 4;
  float* E2            = (float*)wsb;           wsb += (size_t)BB * CDIM * 4;
  float* part          = (float*)wsb;           wsb += (size_t)BB * 16 * HH * 4;
  float* outp = (float*)d_out;

  kc_convert<<<6144 + 768, 256, 0, stream>>>(hidden, dense_W, hbf, WtopT);
  k1_stats<<<dim3(17, BB), 256, 0, stream>>>(hidden, spans, part, nodes, cover);
  k2_gat<<<BB, 256, 0, stream>>>(part, nodes, spans, W1, a_src1, a_dst1, b1, ln_g, ln_b,
                                 W2, a_src2, a_dst2, b2, dense_W, E2);
  k3_dense<<<dim3(CDIM / 128, (BB * SS) / 128), 256, 0, stream>>>(hbf, WtopT, dense_b,
                                                                  cover, E2, qkb);
  k4_ropeaug<<<(BB * SS) / 8, 256, 0, stream>>>(qkb, spans, corr, gc, gs, gw, Qa, Ka);
  k5_logits<<<dim3(8, 8, BB * TT), 256, 0, stream>>>(Qa, Ka, amask, outp);
}